// Round 2
// baseline (2101.155 us; speedup 1.0000x reference)
//
#include <hip/hip_runtime.h>
#include <hip/hip_bf16.h>

#define T 2048
#define H 2560
#define NE 8
#define ITXT 1536
#define IIMG 512
#define ISH 3072
#define CAP 2048

// GEMM tiling
#define MT 128
#define NT 32
#define BK 64
#define LSTR 72   // BK + 8 pad; row = 144B = 36 banks (gcd(36,32)=4), 16B-aligned rows

using bf16 = __hip_bfloat16;
typedef short short8 __attribute__((ext_vector_type(8)));
typedef float float4v __attribute__((ext_vector_type(4)));

// ---- workspace layout (bytes) ----
static constexpr size_t OFF_XBF  = 0;                                   // bf16[T*H]
static constexpr size_t OFF_CNT  = OFF_XBF + (size_t)T * H * 2;         // int[32]
static constexpr size_t OFF_TOK  = OFF_CNT + 128;                       // int[17][CAP]
static constexpr size_t OFF_WTS  = OFF_TOK + (size_t)17 * CAP * 4;      // float[17][CAP]
static constexpr size_t OFF_HTXT = OFF_WTS + (size_t)17 * CAP * 4;      // bf16[8][CAP][ITXT]
static constexpr size_t OFF_HIMG = OFF_HTXT + (size_t)NE * CAP * ITXT * 2;
static constexpr size_t OFF_HSH  = OFF_HIMG + (size_t)NE * CAP * IIMG * 2;

__device__ __forceinline__ unsigned short f2bf(float f) {
    bf16 b = __float2bfloat16(f);
    unsigned short u;
    __builtin_memcpy(&u, &b, 2);
    return u;
}
__device__ __forceinline__ unsigned pack2(float a, float b) {
    return (unsigned)f2bf(a) | ((unsigned)f2bf(b) << 16);
}

// ---- cast x to bf16 + init shared bucket ----
__global__ void k_cast_init(const float* __restrict__ x, bf16* __restrict__ xb,
                            int* __restrict__ counts, int* __restrict__ toks,
                            float* __restrict__ wts) {
    int i = blockIdx.x * blockDim.x + threadIdx.x;   // < T*H/4
    float4 v = ((const float4*)x)[i];
    ushort4 p;
    p.x = f2bf(v.x); p.y = f2bf(v.y); p.z = f2bf(v.z); p.w = f2bf(v.w);
    *(ushort4*)(xb + 4 * (size_t)i) = p;
    if (i < CAP) { toks[16 * CAP + i] = i; wts[16 * CAP + i] = 1.0f; }
    if (i == 0) counts[16] = T;
}

// ---- router: one wave per token ----
__global__ void k_router(const float* __restrict__ x, const int* __restrict__ vmask,
                         const float* __restrict__ tg, const float* __restrict__ ig,
                         int* __restrict__ counts, int* __restrict__ toks,
                         float* __restrict__ wts) {
    int wave = threadIdx.x >> 6;
    int lane = threadIdx.x & 63;
    int t = blockIdx.x * 4 + wave;
    if (t >= T) return;
    bool vis = vmask[t] != 0;
    const float* gw = vis ? ig : tg;
    const float* xr = x + (size_t)t * H;
    float logits[NE];
#pragma unroll
    for (int e = 0; e < NE; ++e) {
        const float* g = gw + (size_t)e * H;
        double s = 0.0;
        for (int h = lane; h < H; h += 64) s += (double)xr[h] * (double)g[h];
#pragma unroll
        for (int off = 32; off > 0; off >>= 1) s += __shfl_xor(s, off);
        logits[e] = (float)s;
    }
    if (lane == 0) {
        int e1 = 0;
#pragma unroll
        for (int e = 1; e < NE; ++e) if (logits[e] > logits[e1]) e1 = e;
        int e2 = -1;
#pragma unroll
        for (int e = 0; e < NE; ++e)
            if (e != e1 && (e2 < 0 || logits[e] > logits[e2])) e2 = e;
        float w1 = 1.0f / (1.0f + expf(logits[e2] - logits[e1]));
        float w2 = 1.0f - w1;
        int b = vis ? 8 : 0;
        int s1 = atomicAdd(&counts[b + e1], 1);
        toks[(b + e1) * CAP + s1] = t; wts[(b + e1) * CAP + s1] = w1;
        int s2 = atomicAdd(&counts[b + e2], 1);
        toks[(b + e2) * CAP + s2] = t; wts[(b + e2) * CAP + s2] = w2;
    }
}

// ============ gate+up grouped GEMM (register-prefetch double buffer) ============
// h = silu(A*Bg) * (A*Bu); A gathered from x_bf via token list
__global__ __launch_bounds__(256, 3) void k_gateup(
    const float* __restrict__ Bg, const float* __restrict__ Bu,
    int ldb, int K, size_t wstride,
    const bf16* __restrict__ A, int lda,
    const int* __restrict__ counts, const int* __restrict__ toks, int bucket_base,
    bf16* __restrict__ hout, int hstr, size_t hestride) {
    int e = blockIdx.z;
    int bucket = bucket_base + e;
    int cnt = counts[bucket];
    int m0 = blockIdx.y * MT;
    if (m0 >= cnt) return;
    int n0 = blockIdx.x * NT;
    const float* bg = Bg + (size_t)e * wstride;
    const float* bu = Bu + (size_t)e * wstride;
    const int* tk = toks + (size_t)bucket * CAP;

    __shared__ bf16 As[MT][LSTR];
    __shared__ bf16 Bs[2][NT][LSTR];

    int tid = threadIdx.x;
    int lane = tid & 63;
    int wv = tid >> 6;          // wave -> m strip of 32

    // A staging: 128 rows x 64 bf16; 2 threads/row, 32 elems each
    int rr = tid >> 1;
    int ac = (tid & 1) * 32;
    int arow = min(m0 + rr, cnt - 1);         // clamp: garbage rows masked in epilogue
    const bf16* aptr = A + (size_t)tk[arow] * lda + ac;

    // B staging: 64k x 32n fp32 per matrix; thread covers 4k x 2n
    int nb = (tid & 15) * 2;
    int kb = (tid >> 4) * 4;
    const float* bgp = bg + (size_t)kb * ldb + n0 + nb;
    const float* bup = bu + (size_t)kb * ldb + n0 + nb;

    uint4 apre[4];
    float2 gpre[4], upre[4];

    auto loadtile = [&](int k0) {
#pragma unroll
        for (int i = 0; i < 4; ++i)
            apre[i] = *(const uint4*)(aptr + k0 + i * 8);
        const float* g0 = bgp + (size_t)k0 * ldb;
        const float* u0 = bup + (size_t)k0 * ldb;
#pragma unroll
        for (int r = 0; r < 4; ++r) {
            gpre[r] = *(const float2*)(g0 + (size_t)r * ldb);
            upre[r] = *(const float2*)(u0 + (size_t)r * ldb);
        }
    };
    auto storetile = [&]() {
#pragma unroll
        for (int i = 0; i < 4; ++i)
            *(uint4*)&As[rr][ac + i * 8] = apre[i];
        uint2 w;
        w.x = pack2(gpre[0].x, gpre[1].x); w.y = pack2(gpre[2].x, gpre[3].x);
        *(uint2*)&Bs[0][nb][kb] = w;
        w.x = pack2(gpre[0].y, gpre[1].y); w.y = pack2(gpre[2].y, gpre[3].y);
        *(uint2*)&Bs[0][nb + 1][kb] = w;
        w.x = pack2(upre[0].x, upre[1].x); w.y = pack2(upre[2].x, upre[3].x);
        *(uint2*)&Bs[1][nb][kb] = w;
        w.x = pack2(upre[0].y, upre[1].y); w.y = pack2(upre[2].y, upre[3].y);
        *(uint2*)&Bs[1][nb + 1][kb] = w;
    };

    float4v accg[2][2], accu[2][2];
#pragma unroll
    for (int i = 0; i < 2; ++i)
#pragma unroll
        for (int j = 0; j < 2; ++j) { accg[i][j] = (float4v)0.0f; accu[i][j] = (float4v)0.0f; }

    int fr = lane & 15;
    int fq = lane >> 4;

    loadtile(0);
    for (int k0 = 0; k0 < K; k0 += BK) {
        __syncthreads();
        storetile();
        __syncthreads();
        if (k0 + BK < K) loadtile(k0 + BK);
#pragma unroll
        for (int s = 0; s < 2; ++s) {
            int fk = s * 32 + fq * 8;
            short8 af[2], bgf[2], buf2[2];
#pragma unroll
            for (int i = 0; i < 2; ++i) af[i] = *(const short8*)&As[wv * 32 + i * 16 + fr][fk];
#pragma unroll
            for (int j = 0; j < 2; ++j) {
                bgf[j]  = *(const short8*)&Bs[0][j * 16 + fr][fk];
                buf2[j] = *(const short8*)&Bs[1][j * 16 + fr][fk];
            }
#pragma unroll
            for (int i = 0; i < 2; ++i)
#pragma unroll
                for (int j = 0; j < 2; ++j) {
                    accg[i][j] = __builtin_amdgcn_mfma_f32_16x16x32_bf16(af[i], bgf[j],  accg[i][j], 0, 0, 0);
                    accu[i][j] = __builtin_amdgcn_mfma_f32_16x16x32_bf16(af[i], buf2[j], accu[i][j], 0, 0, 0);
                }
        }
    }
    // epilogue: silu(g)*u -> bf16 h
    int cc = lane & 15;
    bf16* hb = hout + hestride * (size_t)e;
#pragma unroll
    for (int i = 0; i < 2; ++i)
#pragma unroll
        for (int j = 0; j < 2; ++j)
#pragma unroll
            for (int r = 0; r < 4; ++r) {
                int ml = m0 + wv * 32 + i * 16 + fq * 4 + r;
                if (ml < cnt) {
                    int col = n0 + j * 16 + cc;
                    float g = accg[i][j][r], u = accu[i][j][r];
                    float hv = g / (1.0f + expf(-g)) * u;
                    hb[(size_t)ml * hstr + col] = __float2bfloat16(hv);
                }
            }
}

// ============ down grouped GEMM ============
// y = (h * Bd) * w[row]; store (accum=0) or atomicAdd (accum=1) into out[tok]
__global__ __launch_bounds__(256, 3) void k_down(
    const float* __restrict__ Bw, int ldb, int K, size_t wstride,
    const bf16* __restrict__ Abase, size_t aestride, int lda,
    const int* __restrict__ counts, const int* __restrict__ toks,
    const float* __restrict__ wts, int bucket_base,
    float* __restrict__ out, int accum) {
    int e = blockIdx.z;
    int bucket = bucket_base + e;
    int cnt = counts[bucket];
    int m0 = blockIdx.y * MT;
    if (m0 >= cnt) return;
    int n0 = blockIdx.x * NT;
    const float* bw = Bw + (size_t)e * wstride;
    const bf16* Ab = Abase + (size_t)e * aestride;

    __shared__ bf16 As[MT][LSTR];
    __shared__ bf16 Bs[NT][LSTR];

    int tid = threadIdx.x;
    int lane = tid & 63;
    int wv = tid >> 6;

    int rr = tid >> 1;
    int ac = (tid & 1) * 32;
    const bf16* aptr = Ab + (size_t)(m0 + rr) * lda + ac;   // rows < CAP: safe, masked later

    int nb = (tid & 15) * 2;
    int kb = (tid >> 4) * 4;
    const float* bwp = bw + (size_t)kb * ldb + n0 + nb;

    uint4 apre[4];
    float2 wpre[4];

    auto loadtile = [&](int k0) {
#pragma unroll
        for (int i = 0; i < 4; ++i)
            apre[i] = *(const uint4*)(aptr + k0 + i * 8);
        const float* b0 = bwp + (size_t)k0 * ldb;
#pragma unroll
        for (int r = 0; r < 4; ++r)
            wpre[r] = *(const float2*)(b0 + (size_t)r * ldb);
    };
    auto storetile = [&]() {
#pragma unroll
        for (int i = 0; i < 4; ++i)
            *(uint4*)&As[rr][ac + i * 8] = apre[i];
        uint2 w;
        w.x = pack2(wpre[0].x, wpre[1].x); w.y = pack2(wpre[2].x, wpre[3].x);
        *(uint2*)&Bs[nb][kb] = w;
        w.x = pack2(wpre[0].y, wpre[1].y); w.y = pack2(wpre[2].y, wpre[3].y);
        *(uint2*)&Bs[nb + 1][kb] = w;
    };

    float4v acc[2][2];
#pragma unroll
    for (int i = 0; i < 2; ++i)
#pragma unroll
        for (int j = 0; j < 2; ++j) acc[i][j] = (float4v)0.0f;

    int fr = lane & 15;
    int fq = lane >> 4;

    loadtile(0);
    for (int k0 = 0; k0 < K; k0 += BK) {
        __syncthreads();
        storetile();
        __syncthreads();
        if (k0 + BK < K) loadtile(k0 + BK);
#pragma unroll
        for (int s = 0; s < 2; ++s) {
            int fk = s * 32 + fq * 8;
            short8 af[2], bf_[2];
#pragma unroll
            for (int i = 0; i < 2; ++i) af[i] = *(const short8*)&As[wv * 32 + i * 16 + fr][fk];
#pragma unroll
            for (int j = 0; j < 2; ++j) bf_[j] = *(const short8*)&Bs[j * 16 + fr][fk];
#pragma unroll
            for (int i = 0; i < 2; ++i)
#pragma unroll
                for (int j = 0; j < 2; ++j)
                    acc[i][j] = __builtin_amdgcn_mfma_f32_16x16x32_bf16(af[i], bf_[j], acc[i][j], 0, 0, 0);
        }
    }
    int cc = lane & 15;
    const int* tkl = toks + (size_t)bucket * CAP;
    const float* wl = wts + (size_t)bucket * CAP;
#pragma unroll
    for (int i = 0; i < 2; ++i)
#pragma unroll
        for (int j = 0; j < 2; ++j)
#pragma unroll
            for (int r = 0; r < 4; ++r) {
                int ml = m0 + wv * 32 + i * 16 + fq * 4 + r;
                if (ml < cnt) {
                    int col = n0 + j * 16 + cc;
                    int tok = tkl[ml];
                    float v = acc[i][j][r] * wl[ml];
                    float* dst = &out[(size_t)tok * H + col];
                    if (accum) atomicAdd(dst, v);
                    else *dst = v;
                }
            }
}

extern "C" void kernel_launch(void* const* d_in, const int* in_sizes, int n_in,
                              void* d_out, int out_size, void* d_ws, size_t ws_size,
                              hipStream_t stream) {
    const float* x    = (const float*)d_in[0];
    const int*   vm   = (const int*)d_in[1];
    const float* tg   = (const float*)d_in[2];
    const float* twg  = (const float*)d_in[3];
    const float* twu  = (const float*)d_in[4];
    const float* twd  = (const float*)d_in[5];
    const float* ig   = (const float*)d_in[6];
    const float* iwg  = (const float*)d_in[7];
    const float* iwu  = (const float*)d_in[8];
    const float* iwd  = (const float*)d_in[9];
    const float* swg  = (const float*)d_in[10];
    const float* swu  = (const float*)d_in[11];
    const float* swd  = (const float*)d_in[12];
    float* out = (float*)d_out;
    char* ws = (char*)d_ws;

    bf16* xb     = (bf16*)(ws + OFF_XBF);
    int*  counts = (int*)(ws + OFF_CNT);
    int*  toks   = (int*)(ws + OFF_TOK);
    float* wtsp  = (float*)(ws + OFF_WTS);
    bf16* htxt   = (bf16*)(ws + OFF_HTXT);
    bf16* himg   = (bf16*)(ws + OFF_HIMG);
    bf16* hsh    = (bf16*)(ws + OFF_HSH);

    hipMemsetAsync(counts, 0, 128, stream);

    k_cast_init<<<dim3((T * H / 4) / 256), dim3(256), 0, stream>>>(x, xb, counts, toks, wtsp);
    k_router<<<dim3(T / 4), dim3(256), 0, stream>>>(x, vm, tg, ig, counts, toks, wtsp);

    // gate+up: text / image / shared
    k_gateup<<<dim3(ITXT / NT, CAP / MT, NE), dim3(256), 0, stream>>>(
        twg, twu, ITXT, H, (size_t)H * ITXT, xb, H, counts, toks, 0,
        htxt, ITXT, (size_t)CAP * ITXT);
    k_gateup<<<dim3(IIMG / NT, CAP / MT, NE), dim3(256), 0, stream>>>(
        iwg, iwu, IIMG, H, (size_t)H * IIMG, xb, H, counts, toks, 8,
        himg, IIMG, (size_t)CAP * IIMG);
    k_gateup<<<dim3(ISH / NT, CAP / MT, 1), dim3(256), 0, stream>>>(
        swg, swu, ISH, H, 0, xb, H, counts, toks, 16,
        hsh, ISH, 0);

    // down: shared FIRST with plain stores (covers every out element), then MoE atomics
    k_down<<<dim3(H / NT, CAP / MT, 1), dim3(256), 0, stream>>>(
        swd, H, ISH, 0, hsh, 0, ISH,
        counts, toks, wtsp, 16, out, 0);
    k_down<<<dim3(H / NT, CAP / MT, NE), dim3(256), 0, stream>>>(
        twd, H, ITXT, (size_t)ITXT * H, htxt, (size_t)CAP * ITXT, ITXT,
        counts, toks, wtsp, 0, out, 1);
    k_down<<<dim3(H / NT, CAP / MT, NE), dim3(256), 0, stream>>>(
        iwd, H, IIMG, (size_t)IIMG * H, himg, (size_t)CAP * IIMG, IIMG,
        counts, toks, wtsp, 8, out, 1);
}